// Round 17
// baseline (28.457 us; speedup 1.0000x reference)
//
#include <hip/hip_runtime.h>

// LinearAccInterpolation: B x (NKP keyframes) x DIM=2.
// Per segment i (n = idx[i+1]-idx[i]):
//   da = (dy - n*v0 - n(n+1)/2*a0) / (n(n+1)(n+2)/6)
//   pos_k = y0 + k*v0 + k(k+1)/2*a0 + k(k+1)(k+2)/6*da   (k=1..n)
//   v0 += n*a0 + n(n+1)/2*da ;  a0 += n*da
// n<=1: emit y1; a0 = (y1-y0) - v0; v0 = y1-y0.
//
// LESSONS (measured):
//  R6: store coalescing is per WAVE INSTRUCTION; partial lines amplify writes.
//  R7: LDS in a runtime-trip dependent chain = latency-bound.
//  R8/R10: few blocks / long in-block pipelines = latency-bound.
//  R11+R15 A/B x2: nontemporal stores beat plain by ~14% on this stream.
//  R12: 20x-redundant recurrence = VALU-chain-bound.
//  R13/R14: wave-local phases, zero barriers -> 21.65us (best).
//  R16: ds_swizzle pattern must be a compile-time constant -> template param.
// R17 = R16 fixed: per segment-pair, two ds_swizzle quad-perms (0x808D,
//  0x80D8) redistribute the 4-lane group's 8 rows so each lane assembles
//  one f4 chunk (rows 2c,2c+1) and nt-stores it directly: group writes one
//  full aligned 64B line per instruction, 16 lines/wave-instruction (same
//  line count as R14's 1KB burst). Stores spread across compute;
//  LDS = inputs only (6.6KB); 0 barriers.

typedef float f4 __attribute__((ext_vector_type(4)));

template <int PAT>
__device__ __forceinline__ float swz(float x) {
    return __int_as_float(__builtin_amdgcn_ds_swizzle(__float_as_int(x), PAT));
}

template <int NSEG>
__global__ __launch_bounds__(256) void interp_fast(
    const int* __restrict__ index,
    const float2* __restrict__ value,      // B x NKP
    const float2* __restrict__ vinit,      // B x 1
    const float2* __restrict__ ainit,      // B x 1
    float2* __restrict__ out,              // B x rows (rows = 4*NSEG)
    int B)
{
    constexpr int NKP  = NSEG + 1;         // 11
    constexpr int ROWS = 4 * NSEG;         // 40
    constexpr int RF4  = ROWS / 2;         // 20 f4 chunks per batch
    constexpr int WB   = 16;               // batches per wave
    constexpr int WF2  = WB * NKP;         // 176 f2 of keyframes per wave
    constexpr int QP1  = 0x808D;           // quad perm [1,3,0,2]
    constexpr int QP2  = 0x80D8;           // quad perm [0,2,1,3]

    __shared__ float2 sv[64 * NKP];        // input staging only (linear)
    __shared__ float2 svi[64];
    __shared__ float2 sai[64];

    int tid = threadIdx.x;
    int w   = tid >> 6;                    // wave 0..3
    int l   = tid & 63;
    int first_b = blockIdx.x * 64;

    int xi[NKP];
#pragma unroll
    for (int i = 0; i < NKP; ++i) xi[i] = index[i];    // uniform -> scalar

    // ---- wave-local staging (no barrier; linear LDS layout) ----
    {
        const float2* gv = value + (long)first_b * NKP;
#pragma unroll
        for (int t = 0; t < (WF2 + 63) / 64; ++t) {
            int fo = t * 64 + l;
            if (fo < WF2) {
                int f = w * WF2 + fo;
                sv[f] = gv[f];
            }
        }
        int wb = w * WB;
        if (l < WB) svi[wb + l] = vinit[first_b + wb + l];
        else if (l < 2 * WB) sai[wb + l - WB] = ainit[first_b + wb + l - WB];
    }

    bool fast = true;
#pragma unroll
    for (int i = 0; i < NSEG; ++i) fast = fast && (xi[i + 1] - xi[i] == 4);

    // ---- B1: wave-local LDS -> registers ----
    int bl = tid >> 2;                     // wave-local batch (16w + l>>2)
    int r  = tid & 3;                      // lane-in-group
    const float2* __restrict__ row = sv + bl * NKP;

    float2 y[NKP];
#pragma unroll
    for (int i = 0; i < NKP; ++i) y[i] = row[i];       // 4-lane broadcast reads
    float2 v0 = svi[bl];
    float2 a0 = sai[bl];

    if (fast) {
        // lane r computes row k=r+1 of every segment; per segment-pair,
        // two quad-perm swizzles assemble each lane's f4 chunk.
        float fk = (float)(r + 1);
        float t2 = fk * (fk + 1.0f) * 0.5f;
        float t3 = t2 * (fk + 2.0f) * (1.0f / 3.0f);

        f4* __restrict__ o4 = (f4*)out + (long)first_b * RF4 + bl * RF4 + r;

#pragma unroll
        for (int j = 0; j < NSEG / 2; ++j) {
            // ---- segment i0 = 2j ----
            float2 y0 = y[2 * j];
            float2 y1 = y[2 * j + 1];
            float dyx = y1.x - y0.x;
            float dyy = y1.y - y0.y;
            float dax = (dyx - 4.0f * v0.x - 10.0f * a0.x) * 0.05f;
            float day = (dyy - 4.0f * v0.y - 10.0f * a0.y) * 0.05f;
            float2 p;                      // own row of seg i0
            p.x = y0.x + fk * v0.x + t2 * a0.x + t3 * dax;
            p.y = y0.y + fk * v0.y + t2 * a0.y + t3 * day;
            v0.x += 4.0f * a0.x + 10.0f * dax;
            v0.y += 4.0f * a0.y + 10.0f * day;
            a0.x += 4.0f * dax;
            a0.y += 4.0f * day;

            // ---- segment i1 = 2j+1 ----
            float2 z0 = y1;
            float2 z1 = y[2 * j + 2];
            float dzx = z1.x - z0.x;
            float dzy = z1.y - z0.y;
            float dbx = (dzx - 4.0f * v0.x - 10.0f * a0.x) * 0.05f;
            float dby = (dzy - 4.0f * v0.y - 10.0f * a0.y) * 0.05f;
            float2 pp;                     // own row of seg i1
            pp.x = z0.x + fk * v0.x + t2 * a0.x + t3 * dbx;
            pp.y = z0.y + fk * v0.y + t2 * a0.y + t3 * dby;
            v0.x += 4.0f * a0.x + 10.0f * dbx;
            v0.y += 4.0f * a0.y + 10.0f * dby;
            a0.x += 4.0f * dbx;
            a0.y += 4.0f * dby;

            // ---- redistribute within the 4-lane group ----
            // O1: odd lanes supply p (seg i0), even lanes supply pp (seg i1)
            bool odd = (r & 1);
            float o1x = odd ? p.x : pp.x;
            float o1y = odd ? p.y : pp.y;
            float t1x = swz<QP1>(o1x);     // l0<-l1.p  l1<-l3.p  l2<-l0.pp  l3<-l2.pp
            float t1y = swz<QP1>(o1y);
            // O2: lane2 supplies p, lane1 supplies pp (others unused)
            float o2x = (r == 2) ? p.x : pp.x;
            float o2y = (r == 2) ? p.y : pp.y;
            float t2x = swz<QP2>(o2x);     // l1<-l2.p  l2<-l1.pp
            float t2y = swz<QP2>(o2y);

            // assemble chunk: l0=(p,t1) l1=(t2,t1) l2=(t1,t2) l3=(t1,pp)
            f4 o;
            o.x = (r == 0) ? p.x : (r == 1) ? t2x : t1x;
            o.y = (r == 0) ? p.y : (r == 1) ? t2y : t1y;
            o.z = (r < 2) ? t1x : (r == 2) ? t2x : pp.x;
            o.w = (r < 2) ? t1y : (r == 2) ? t2y : pp.y;

            // lane r stores chunk 4j+r: group covers one full 64B line
            __builtin_nontemporal_store(o, o4 + 4 * j);
        }
    } else {
        // generic fallback (never taken for uniform n==4): direct predicated
        // global stores, lane r handles rows k=r+1 step 4 per segment.
        float2* __restrict__ orow = out + ((long)first_b + bl) * ROWS;
        int off = 0;
#pragma unroll
        for (int i = 0; i < NSEG; ++i) {
            float2 y0 = y[i];
            float2 y1 = y[i + 1];
            int n = xi[i + 1] - xi[i];
            float dyx = y1.x - y0.x;
            float dyy = y1.y - y0.y;
            if (n <= 1) {
                if (r == 0 && off < ROWS) orow[off] = y1;
                off += 1;
                a0.x = dyx - v0.x;
                a0.y = dyy - v0.y;
                v0.x = dyx;
                v0.y = dyy;
            } else {
                float fn = (float)n;
                float c1 = fn * (fn + 1.0f) * 0.5f;
                float c2 = fn * (fn + 1.0f) * (fn + 2.0f) / 6.0f;
                float rc2 = __builtin_amdgcn_rcpf(c2);
                float dax = (dyx - fn * v0.x - c1 * a0.x) * rc2;
                float day = (dyy - fn * v0.y - c1 * a0.y) * rc2;
                for (int k = r + 1; k <= n; k += 4) {
                    int g = off + k - 1;
                    if (g < ROWS) {
                        float gk = (float)k;
                        float g2 = gk * (gk + 1.0f) * 0.5f;
                        float g3 = gk * (gk + 1.0f) * (gk + 2.0f) * (1.0f / 6.0f);
                        float2 q;
                        q.x = y0.x + gk * v0.x + g2 * a0.x + g3 * dax;
                        q.y = y0.y + gk * v0.y + g2 * a0.y + g3 * day;
                        orow[g] = q;
                    }
                }
                off += n;
                v0.x += fn * a0.x + c1 * dax;
                v0.y += fn * a0.y + c1 * day;
                a0.x += fn * dax;
                a0.y += fn * day;
            }
        }
    }
}

// Runtime fallback for unexpected nkp/rows/B: one thread per (batch, 8-row
// chunk), rolling y loads, predicated direct stores (R11-proven).
__global__ __launch_bounds__(256) void interp_gen(
    const int* __restrict__ index,
    const float2* __restrict__ value,
    const float2* __restrict__ vinit,
    const float2* __restrict__ ainit,
    float2* __restrict__ out,
    int B, int nkp, int rows, int PT)
{
    long t = (long)blockIdx.x * 256 + threadIdx.x;
    long total = (long)B * PT;
    if (t >= total) return;
    int b = (int)(t / PT);
    int j = (int)(t - (long)b * PT);
    int g_lo = j * 8;
    int g_hi = g_lo + 8;
    if (g_hi > rows) g_hi = rows;

    const float2* __restrict__ vrow = value + (long)b * nkp;
    float2* __restrict__ orow = out + (long)b * rows;
    float2 v0 = vinit[b];
    float2 a0 = ainit[b];
    float2 y0 = vrow[0];
    int x0 = index[0];
    int off = 0;
    for (int i = 0; i < nkp - 1; ++i) {
        float2 y1 = vrow[i + 1];
        int x1 = index[i + 1];
        int n = x1 - x0; x0 = x1;
        float dyx = y1.x - y0.x, dyy = y1.y - y0.y;
        if (n <= 1) {
            if (off >= g_lo && off < g_hi) orow[off] = y1;
            off += 1;
            a0.x = dyx - v0.x; a0.y = dyy - v0.y;
            v0.x = dyx; v0.y = dyy;
        } else {
            float fn = (float)n;
            float c1 = fn * (fn + 1.0f) * 0.5f;
            float c2 = fn * (fn + 1.0f) * (fn + 2.0f) / 6.0f;
            float dax = (dyx - fn * v0.x - c1 * a0.x) / c2;
            float day = (dyy - fn * v0.y - c1 * a0.y) / c2;
            for (int k = 1; k <= n; ++k) {
                int g = off + k - 1;
                if (g >= g_lo && g < g_hi) {
                    float fkk = (float)k;
                    float t2 = fkk * (fkk + 1.0f) * 0.5f;
                    float t3 = fkk * (fkk + 1.0f) * (fkk + 2.0f) * (1.0f / 6.0f);
                    float2 p;
                    p.x = y0.x + fkk * v0.x + t2 * a0.x + t3 * dax;
                    p.y = y0.y + fkk * v0.y + t2 * a0.y + t3 * day;
                    orow[g] = p;
                }
            }
            off += n;
            v0.x += fn * a0.x + c1 * dax;
            v0.y += fn * a0.y + c1 * day;
            a0.x += fn * dax;
            a0.y += fn * day;
        }
        y0 = y1;
    }
}

extern "C" void kernel_launch(void* const* d_in, const int* in_sizes, int n_in,
                              void* d_out, int out_size, void* d_ws, size_t ws_size,
                              hipStream_t stream) {
    const int*    index = (const int*)d_in[0];
    const float2* value = (const float2*)d_in[1];
    const float2* vinit = (const float2*)d_in[2];
    const float2* ainit = (const float2*)d_in[3];
    float2*       out   = (float2*)d_out;

    int nkp  = in_sizes[0];                 // 11
    int B    = in_sizes[1] / (nkp * 2);     // 262144
    int rows = out_size / (B * 2);          // 40

    if (nkp == 11 && rows == 40 && (B % 64) == 0) {
        dim3 grid(B / 64);                  // 4096 blocks of TLP
        interp_fast<10><<<grid, 256, 0, stream>>>(index, value, vinit, ainit, out, B);
    } else {
        int PT = (rows + 7) / 8;
        long total = (long)B * PT;
        dim3 grid((unsigned)((total + 255) / 256));
        interp_gen<<<grid, 256, 0, stream>>>(index, value, vinit, ainit, out, B, nkp, rows, PT);
    }
}

// Round 18
// 22.140 us; speedup vs baseline: 1.2853x; 1.2853x over previous
//
#include <hip/hip_runtime.h>

// LinearAccInterpolation: B x (NKP keyframes) x DIM=2.
// Per segment i (n = idx[i+1]-idx[i]):
//   da = (dy - n*v0 - n(n+1)/2*a0) / (n(n+1)(n+2)/6)
//   pos_k = y0 + k*v0 + k(k+1)/2*a0 + k(k+1)(k+2)/6*da   (k=1..n)
//   v0 += n*a0 + n(n+1)/2*da ;  a0 += n*da
// n<=1: emit y1; a0 = (y1-y0) - v0; v0 = y1-y0.
//
// FINAL (= R14, best measured 21.65us). LESSONS (all measured):
//  R6: store coalescing is per WAVE INSTRUCTION; partial lines = 1.68x
//      write amplification.
//  R17: even FULL lines at 320B stride per wave instruction drain ~30%
//      slower than fully-contiguous 1KB bursts -> the LDS out-tile exists
//      to buy store contiguity, not just reshape.
//  R7: LDS in a runtime-trip dependent chain = latency-bound.
//  R8/R10: few blocks / long in-block pipelines = latency-bound; TLP wins.
//  R11+R15 A/B x2: nontemporal beats plain by ~14% on this stream.
//  R12: 20x-redundant recurrence = VALU-chain-bound.
//  R13->R14: wave-local phases allow ONE then ZERO barriers (same-wave DS
//      program order is sufficient when each wave owns its batches for
//      staging, compute, and copy-out).

typedef float f4 __attribute__((ext_vector_type(4)));

template <int NSEG>
__global__ __launch_bounds__(256) void interp_fast(
    const int* __restrict__ index,
    const float2* __restrict__ value,      // B x NKP
    const float2* __restrict__ vinit,      // B x 1
    const float2* __restrict__ ainit,      // B x 1
    float2* __restrict__ out,              // B x rows (rows = 4*NSEG)
    int B)
{
    constexpr int NKP  = NSEG + 1;         // 11
    constexpr int ROWS = 4 * NSEG;         // 40
    constexpr int PAD2 = ROWS + 2;         // 42 f2 = 336B = 21 f4 per batch
    constexpr int RF4  = ROWS / 2;         // 20 f4 chunks per batch
    constexpr int PF4  = PAD2 / 2;         // 21
    constexpr int WB   = 16;               // batches per wave
    constexpr int WF2  = WB * NKP;         // 176 f2 of keyframes per wave

    __shared__ float2 lds2[64 * PAD2];     // out tile; inputs parked in [*][0..10]
    __shared__ float2 svi[64];
    __shared__ float2 sai[64];

    int tid = threadIdx.x;
    int w   = tid >> 6;                    // wave 0..3
    int l   = tid & 63;
    int first_b = blockIdx.x * 64;

    // uniform segment lengths (hoisted; scalar loads overlap staging)
    int xi[NKP];
#pragma unroll
    for (int i = 0; i < NKP; ++i) xi[i] = index[i];

    // ---- wave-local staging (NO barrier afterwards) ----
    {
        const float2* gv = value + (long)first_b * NKP;
#pragma unroll
        for (int t = 0; t < (WF2 + 63) / 64; ++t) {
            int fo = t * 64 + l;
            if (fo < WF2) {
                int f  = w * WF2 + fo;
                int bb = f / NKP;          // const div -> magic mul
                int j  = f - bb * NKP;
                lds2[bb * PAD2 + j] = gv[f];
            }
        }
        int wb = w * WB;
        if (l < WB) svi[wb + l] = vinit[first_b + wb + l];
        else if (l < 2 * WB) sai[wb + l - WB] = ainit[first_b + wb + l - WB];
    }

    bool fast = true;
#pragma unroll
    for (int i = 0; i < NSEG; ++i) fast = fast && (xi[i + 1] - xi[i] == 4);

    // ---- B1: wave-local LDS -> registers ----
    int bl = tid >> 2;                     // = 16w + (l>>2): wave-local batch
    int r  = tid & 3;                      // lane-in-group
    float2* __restrict__ row = lds2 + bl * PAD2;

    float2 y[NKP];
#pragma unroll
    for (int i = 0; i < NKP; ++i) y[i] = row[i];       // 4-lane broadcast reads
    float2 v0 = svi[bl];
    float2 a0 = sai[bl];

    // ---- B2: recurrence -> own padded row (overwrites own inputs) ----
    if (fast) {
#pragma unroll
        for (int i = 0; i < NSEG; ++i) {
            float2 y0 = y[i];
            float2 y1 = y[i + 1];
            float dyx = y1.x - y0.x;
            float dyy = y1.y - y0.y;
            // n=4: c1=10, c2=20, 1/c2=0.05
            float dax = (dyx - 4.0f * v0.x - 10.0f * a0.x) * 0.05f;
            float day = (dyy - 4.0f * v0.y - 10.0f * a0.y) * 0.05f;

            float fk = (float)(r + 1);     // lane r writes row k=r+1
            float t2 = fk * (fk + 1.0f) * 0.5f;
            float t3 = t2 * (fk + 2.0f) * (1.0f / 3.0f);
            float2 p;
            p.x = y0.x + fk * v0.x + t2 * a0.x + t3 * dax;
            p.y = y0.y + fk * v0.y + t2 * a0.y + t3 * day;
            row[4 * i + r] = p;

            v0.x += 4.0f * a0.x + 10.0f * dax;
            v0.y += 4.0f * a0.y + 10.0f * day;
            a0.x += 4.0f * dax;
            a0.y += 4.0f * day;
        }
    } else {
        // generic n handling; still wave-local
        int off = 0;
#pragma unroll
        for (int i = 0; i < NSEG; ++i) {
            float2 y0 = y[i];
            float2 y1 = y[i + 1];
            int n = xi[i + 1] - xi[i];
            float dyx = y1.x - y0.x;
            float dyy = y1.y - y0.y;
            if (n <= 1) {
                if (r == 0) row[off] = y1;
                off += 1;
                a0.x = dyx - v0.x;
                a0.y = dyy - v0.y;
                v0.x = dyx;
                v0.y = dyy;
            } else {
                float fn = (float)n;
                float c1 = fn * (fn + 1.0f) * 0.5f;
                float c2 = fn * (fn + 1.0f) * (fn + 2.0f) / 6.0f;
                float rc2 = __builtin_amdgcn_rcpf(c2);
                float dax = (dyx - fn * v0.x - c1 * a0.x) * rc2;
                float day = (dyy - fn * v0.y - c1 * a0.y) * rc2;
                for (int k = r + 1; k <= n; k += 4) {
                    float fk = (float)k;
                    float t2 = fk * (fk + 1.0f) * 0.5f;
                    float t3 = fk * (fk + 1.0f) * (fk + 2.0f) * (1.0f / 6.0f);
                    float2 p;
                    p.x = y0.x + fk * v0.x + t2 * a0.x + t3 * dax;
                    p.y = y0.y + fk * v0.y + t2 * a0.y + t3 * day;
                    if (off + k - 1 < ROWS) row[off + k - 1] = p;
                }
                off += n;
                v0.x += fn * a0.x + c1 * dax;
                v0.y += fn * a0.y + c1 * day;
                a0.x += fn * dax;
                a0.y += fn * day;
            }
        }
    }

    // ---- C: wave-local burst copy-out (same-wave DS order; no barrier) ----
    {
        const f4* __restrict__ l4 = (const f4*)lds2;
        f4* __restrict__ o4 = (f4*)out + (long)first_b * RF4;
        int c0 = w * WB * RF4;             // 320 chunks per wave
#pragma unroll
        for (int m = 0; m < WB * RF4 / 64; ++m) {      // 5 iters
            int c  = c0 + m * 64 + l;
            int bb = c / RF4;              // const div -> magic mul
            int j  = c - bb * RF4;
            __builtin_nontemporal_store(l4[bb * PF4 + j], o4 + c);
        }
    }
}

// Runtime fallback for unexpected nkp/rows/B: one thread per (batch, 8-row
// chunk), rolling y loads, predicated direct stores (R11-proven).
__global__ __launch_bounds__(256) void interp_gen(
    const int* __restrict__ index,
    const float2* __restrict__ value,
    const float2* __restrict__ vinit,
    const float2* __restrict__ ainit,
    float2* __restrict__ out,
    int B, int nkp, int rows, int PT)
{
    long t = (long)blockIdx.x * 256 + threadIdx.x;
    long total = (long)B * PT;
    if (t >= total) return;
    int b = (int)(t / PT);
    int j = (int)(t - (long)b * PT);
    int g_lo = j * 8;
    int g_hi = g_lo + 8;
    if (g_hi > rows) g_hi = rows;

    const float2* __restrict__ vrow = value + (long)b * nkp;
    float2* __restrict__ orow = out + (long)b * rows;
    float2 v0 = vinit[b];
    float2 a0 = ainit[b];
    float2 y0 = vrow[0];
    int x0 = index[0];
    int off = 0;
    for (int i = 0; i < nkp - 1; ++i) {
        float2 y1 = vrow[i + 1];
        int x1 = index[i + 1];
        int n = x1 - x0; x0 = x1;
        float dyx = y1.x - y0.x, dyy = y1.y - y0.y;
        if (n <= 1) {
            if (off >= g_lo && off < g_hi) orow[off] = y1;
            off += 1;
            a0.x = dyx - v0.x; a0.y = dyy - v0.y;
            v0.x = dyx; v0.y = dyy;
        } else {
            float fn = (float)n;
            float c1 = fn * (fn + 1.0f) * 0.5f;
            float c2 = fn * (fn + 1.0f) * (fn + 2.0f) / 6.0f;
            float dax = (dyx - fn * v0.x - c1 * a0.x) / c2;
            float day = (dyy - fn * v0.y - c1 * a0.y) / c2;
            for (int k = 1; k <= n; ++k) {
                int g = off + k - 1;
                if (g >= g_lo && g < g_hi) {
                    float fk = (float)k;
                    float t2 = fk * (fk + 1.0f) * 0.5f;
                    float t3 = fk * (fk + 1.0f) * (fk + 2.0f) * (1.0f / 6.0f);
                    float2 p;
                    p.x = y0.x + fk * v0.x + t2 * a0.x + t3 * dax;
                    p.y = y0.y + fk * v0.y + t2 * a0.y + t3 * day;
                    orow[g] = p;
                }
            }
            off += n;
            v0.x += fn * a0.x + c1 * dax;
            v0.y += fn * a0.y + c1 * day;
            a0.x += fn * dax;
            a0.y += fn * day;
        }
        y0 = y1;
    }
}

extern "C" void kernel_launch(void* const* d_in, const int* in_sizes, int n_in,
                              void* d_out, int out_size, void* d_ws, size_t ws_size,
                              hipStream_t stream) {
    const int*    index = (const int*)d_in[0];
    const float2* value = (const float2*)d_in[1];
    const float2* vinit = (const float2*)d_in[2];
    const float2* ainit = (const float2*)d_in[3];
    float2*       out   = (float2*)d_out;

    int nkp  = in_sizes[0];                 // 11
    int B    = in_sizes[1] / (nkp * 2);     // 262144
    int rows = out_size / (B * 2);          // 40

    if (nkp == 11 && rows == 40 && (B % 64) == 0) {
        dim3 grid(B / 64);                  // 4096 blocks of TLP
        interp_fast<10><<<grid, 256, 0, stream>>>(index, value, vinit, ainit, out, B);
    } else {
        int PT = (rows + 7) / 8;
        long total = (long)B * PT;
        dim3 grid((unsigned)((total + 255) / 256));
        interp_gen<<<grid, 256, 0, stream>>>(index, value, vinit, ainit, out, B, nkp, rows, PT);
    }
}